// Round 5
// baseline (487.635 us; speedup 1.0000x reference)
//
#include <hip/hip_runtime.h>
#include <stdint.h>

#define BDIM 32
#define CDIM 32
#define LDIM 1024
#define VDIM 4096
#define BCL (BDIM*CDIM*LDIM)

// ---------------------------------------------------------------- init
__global__ void init_kernel(const float* __restrict__ f, const float* __restrict__ emb,
                            float* __restrict__ f_rest, float* __restrict__ f_hat,
                            float* __restrict__ e_sq, float* __restrict__ loss_acc,
                            unsigned long long* __restrict__ keys, int nkeys) {
    int i = blockIdx.x * blockDim.x + threadIdx.x;
    if (i < BCL) { f_rest[i] = f[i]; f_hat[i] = 0.0f; }
    if (i < VDIM) {
        const float4* e4 = (const float4*)(emb + (size_t)i * CDIM);
        float s = 0.f;
#pragma unroll
        for (int k = 0; k < 8; ++k) {
            float4 v = e4[k];
            s += v.x*v.x; s += v.y*v.y; s += v.z*v.z; s += v.w*v.w;
        }
        e_sq[i] = s;
    }
    if (i < nkeys) keys[i] = ~0ull;
    if (i == 0) *loss_acc = 0.f;
}

// ---------------------------------------------------------------- VQ argmin: register-tiled f32 GEMM
// Block: 256 threads (4 waves). Tile: 128 queries x (vsub*256) codes, K=32 staged once.
// Thread tile 8q x 16v -> 0.75 B/FMA LDS traffic. XOR swizzle keeps b128 LDS reads <=2-way.
// REGALLOC HISTORY (the critical lesson of rounds 2-4):
//   (256,2)  -> 128 VGPR cap, acc[128] spills to SCRATCH (12.8MB writes/dispatch), 142us.
//   default  -> heuristic targets ~4 waves/EU: 136 VGPR + acc parked in AGPRs; every FMA
//               drags v_accvgpr_read/write (VALU 56% = mostly moves), 187us. WORSE.
//   (256,1)  -> declares 1 wave/EU min: full 512-reg budget, acc stays in plain VGPRs
//               (~200 used -> still 2 waves/SIMD resident; grid/LDS bound anyway).
__global__ __launch_bounds__(256, 1) void vq_gemm(
    const float* __restrict__ f_rest, const float* __restrict__ emb,
    const float* __restrict__ e_sq, unsigned long long* __restrict__ keys,
    int lpl, int s, int NQ, int vsub, int vchunks)
{
    const int pl = 1 << lpl;
    const int t  = threadIdx.x;
    const int qt = blockIdx.x / vchunks;
    const int vc = blockIdx.x % vchunks;
    const int qb = qt << 7;

    __shared__ __align__(16) float z_s[128*32];
    __shared__ __align__(16) float e_s[256*32];
    __shared__ float esq_s[256];

    // ---- stage z tile (128 queries x 32 channels), swizzled: idx = qp*32 + (c ^ ((qp&7)<<2))
    for (int rep = 0; rep < 16; ++rep) {
        int idx = rep*256 + t;
        int c  = idx >> 7;
        int qp = idx & 127;
        int q  = qb + qp; if (q >= NQ) q = NQ - 1;
        int b  = q >> lpl;
        int j  = q & (pl - 1);
        float zval;
        if (pl == LDIM) {
            zval = f_rest[b*(CDIM*LDIM) + c*LDIM + j];
        } else {
            int col = j*s + (s>>1) - 1;
            const float* p = f_rest + b*(CDIM*LDIM) + c*LDIM + col;
            zval = 0.5f*(p[0] + p[1]);
        }
        z_s[qp*32 + (c ^ ((qp&7)<<2))] = zval;
    }

    const int tq = t & 15;
    const int tv = t >> 4;

    float bd[8]; int bv[8];
#pragma unroll
    for (int i = 0; i < 8; ++i) { bd[i] = 3.4e38f; bv[i] = 0; }

    const int VB0 = vc * (vsub << 8);
    for (int sub = 0; sub < vsub; ++sub) {
        const int vb = VB0 + (sub << 8);

        // ---- stage e sub-tile (256 codes x 32 c) + esq, swizzled
        for (int r = 0; r < 8; ++r) {
            int idx = r*256 + t;               // float4 id, 0..2047
            int vp = idx >> 3, cq = idx & 7;
            float4 ev = ((const float4*)emb)[(size_t)(vb + vp)*8 + cq];
            *(float4*)&e_s[vp*32 + ((4*cq) ^ ((vp&7)<<2))] = ev;
        }
        esq_s[t] = e_sq[vb + t];
        __syncthreads();

        float acc[128];

        // ---- k4 = 0 peeled: acc = z*e (saves 128 acc-init movs; fp-identical to fma into 0)
        {
            float4 zv[8];
#pragma unroll
            for (int i = 0; i < 8; ++i) {
                int qp = tq + (i << 4);
                zv[i] = *(const float4*)&z_s[qp*32 + ((qp&7)<<2)];
            }
#pragma unroll
            for (int j = 0; j < 16; ++j) {
                int vp = tv + (j << 4);
                float4 ev = *(const float4*)&e_s[vp*32 + ((vp&7)<<2)];
#pragma unroll
                for (int i = 0; i < 8; ++i) {
                    float a = zv[i].x * ev.x;
                    a = fmaf(zv[i].y, ev.y, a);
                    a = fmaf(zv[i].z, ev.z, a);
                    a = fmaf(zv[i].w, ev.w, a);
                    acc[i*16 + j] = a;
                }
            }
        }

        for (int k4 = 1; k4 < 8; ++k4) {
            float4 zv[8];
#pragma unroll
            for (int i = 0; i < 8; ++i) {
                int qp = tq + (i << 4);
                zv[i] = *(const float4*)&z_s[qp*32 + ((4*k4) ^ ((qp&7)<<2))];
            }
#pragma unroll
            for (int j = 0; j < 16; ++j) {
                int vp = tv + (j << 4);
                float4 ev = *(const float4*)&e_s[vp*32 + ((4*k4) ^ ((vp&7)<<2))];
#pragma unroll
                for (int i = 0; i < 8; ++i) {
                    float a = acc[i*16 + j];
                    a = fmaf(zv[i].x, ev.x, a);
                    a = fmaf(zv[i].y, ev.y, a);
                    a = fmaf(zv[i].z, ev.z, a);
                    a = fmaf(zv[i].w, ev.w, a);
                    acc[i*16 + j] = a;
                }
            }
        }

        // biased distance d' = e_sq - 2*dot (zz constant per query); v ascending -> first-index ties
#pragma unroll
        for (int j = 0; j < 16; ++j) {
            int vp = tv + (j << 4);
            float es = esq_s[vp];
            int v = vb + vp;
#pragma unroll
            for (int i = 0; i < 8; ++i) {
                float d = fmaf(acc[i*16 + j], -2.0f, es);
                if (d < bd[i]) { bd[i] = d; bv[i] = v; }
            }
        }
        __syncthreads();
    }

    // ---- in-block reduction across the 16 tv columns (each holds a disjoint code subset).
    // Reuse e_s as u64[16][128] (16 KB), transposed so the reduce reads are conflict-free.
    unsigned long long* red_s = (unsigned long long*)e_s;
#pragma unroll
    for (int i = 0; i < 8; ++i) {
        unsigned ud = __float_as_uint(bd[i]);
        ud = (ud & 0x80000000u) ? ~ud : (ud | 0x80000000u);   // monotone map (handles negatives)
        red_s[tv*128 + tq + (i << 4)] = ((unsigned long long)ud << 32) | (unsigned)bv[i];
    }
    __syncthreads();
    if (t < 128) {
        unsigned long long best = red_s[t];
#pragma unroll
        for (int m = 1; m < 16; ++m) {
            unsigned long long k2 = red_s[m*128 + t];
            if (k2 < best) best = k2;
        }
        int q = qb + t;
        if (q < NQ) atomicMin(&keys[q], best);
    }
}

// ---------------------------------------------------------------- fused gather+upsample+phi+update+loss
__global__ __launch_bounds__(256) void fuse_kernel(
    const float* __restrict__ f, const float* __restrict__ emb,
    const unsigned long long* __restrict__ keys,
    const float* __restrict__ w, const float* __restrict__ bias,
    float* __restrict__ f_rest, float* __restrict__ f_hat,
    float* __restrict__ loss_acc, int pl)
{
    const int t  = threadIdx.x;
    const int b  = blockIdx.y;
    const int l0 = blockIdx.x * 128;

    __shared__ float w_s[3072];      // [o][i][k]
    __shared__ float b_s[32];
    __shared__ float hs[32 * 132];   // [i][130 (+pad)] : col x -> l = l0 - 1 + x
    __shared__ float red[4];

    for (int x = t; x < 3072; x += 256) w_s[x] = w[x];
    if (t < 32) b_s[t] = bias[t];

    if (t < 130) {
        int l = l0 - 1 + t;
        if (l < 0 || l >= LDIM) {
#pragma unroll
            for (int i = 0; i < 32; ++i) hs[i * 132 + t] = 0.f;
        } else {
            int lo, hi; float wg;
            if (pl == LDIM) { lo = l; hi = l; wg = 0.f; }
            else {
                float pos = (l + 0.5f) * ((float)pl / 1024.0f) - 0.5f;
                pos = fminf(fmaxf(pos, 0.f), (float)(pl - 1));
                lo = (int)floorf(pos);
                hi = min(lo + 1, pl - 1);
                wg = pos - (float)lo;
            }
            int v0 = (int)(keys[b * pl + lo] & 0xFFFFFFFFull);
            int v1 = (int)(keys[b * pl + hi] & 0xFFFFFFFFull);
            const float4* e0 = (const float4*)(emb + (size_t)v0 * 32);
            const float4* e1 = (const float4*)(emb + (size_t)v1 * 32);
            float om = 1.0f - wg;
#pragma unroll
            for (int i4 = 0; i4 < 8; ++i4) {
                float4 a = e0[i4]; float4 c = e1[i4];
                hs[(i4*4+0) * 132 + t] = a.x * om + c.x * wg;
                hs[(i4*4+1) * 132 + t] = a.y * om + c.y * wg;
                hs[(i4*4+2) * 132 + t] = a.z * om + c.z * wg;
                hs[(i4*4+3) * 132 + t] = a.w * om + c.w * wg;
            }
        }
    }
    __syncthreads();

    const int o  = t >> 3;        // output channel, fixed per thread (w reuse x16)
    const int lg = t & 7;         // 16 consecutive l's per thread
    const float* wrow = &w_s[o * 96];
    float acc[16];
#pragma unroll
    for (int u = 0; u < 16; ++u) acc[u] = 0.f;
    const int hbase = lg * 16;    // hs col for l = l0 + lg*16 - 1

    for (int i = 0; i < 32; ++i) {
        float w0 = wrow[i * 3 + 0], w1 = wrow[i * 3 + 1], w2 = wrow[i * 3 + 2];
        const float* hrow = &hs[i * 132 + hbase];
        float hw[18];
#pragma unroll
        for (int x = 0; x < 18; ++x) hw[x] = hrow[x];
#pragma unroll
        for (int u = 0; u < 16; ++u) {
            acc[u] = fmaf(w0, hw[u], acc[u]);
            acc[u] = fmaf(w1, hw[u + 1], acc[u]);
            acc[u] = fmaf(w2, hw[u + 2], acc[u]);
        }
    }

    float lsum = 0.f;
    const int gbase = (b * 32 + o) * LDIM + l0 + lg * 16;
#pragma unroll
    for (int u = 0; u < 16; ++u) {
        float hval = hs[o * 132 + lg * 16 + 1 + u];
        float y = acc[u] + b_s[o];
        float ph = 0.5f * hval + 0.5f * y;    // h*(1-RESI) + (conv+b)*RESI, RESI=0.5
        int gi = gbase + u;
        float fh = f_hat[gi] + ph;
        f_hat[gi] = fh;
        f_rest[gi] -= ph;
        float df = fh - f[gi];
        lsum = fmaf(df, df, lsum);
    }

#pragma unroll
    for (int off = 32; off > 0; off >>= 1) lsum += __shfl_down(lsum, off, 64);
    if ((t & 63) == 0) red[t >> 6] = lsum;
    __syncthreads();
    if (t == 0) atomicAdd(loss_acc, red[0] + red[1] + red[2] + red[3]);
}

// ---------------------------------------------------------------- loss finalize
__global__ void final_kernel(const float* __restrict__ loss_acc, float* __restrict__ out_loss) {
    // per scale: (BETA + 1) * sse/BCL ; summed over 6 scales then /6
    *out_loss = (*loss_acc) * (1.25f / (6.0f * (float)BCL));
}

// ---------------------------------------------------------------- launch
extern "C" void kernel_launch(void* const* d_in, const int* in_sizes, int n_in,
                              void* d_out, int out_size, void* d_ws, size_t ws_size,
                              hipStream_t stream)
{
    const float* f    = (const float*)d_in[0];
    const float* emb  = (const float*)d_in[1];
    const float* phiw = (const float*)d_in[2];
    const float* phib = (const float*)d_in[3];

    float* f_hat    = (float*)d_out;        // BCL floats
    float* out_loss = f_hat + BCL;          // +1 float

    const int pls[6]  = {1, 4, 16, 64, 256, 1024};
    const int lpls[6] = {0, 2, 4, 6, 8, 10};
    const int vch[6]  = {16, 16, 16, 16, 8, 2};      // code chunks per query-tile
    const int vsb[6]  = {1, 1, 1, 1, 2, 8};          // 256-code subtiles per block (vch*vsb = 16)
    const int pidx[6] = {0, 0, 1, 2, 3, 3};          // PhiPartiallyShared static tick lookup
    const int qoff[6] = {0, 32, 160, 672, 2720, 10912};  // cumulative NQ (multi-buffer keys)
    const int NKEYS_ALL = 43680;                     // 32*(1+4+16+64+256+1024)

    char* ws = (char*)d_ws;
    float* f_rest            = (float*)ws;                          // 4 MB
    unsigned long long* keys = (unsigned long long*)(ws + (size_t)BCL * 4);

    // Per-scale keys sub-buffers, init once in init_kernel (no per-scale memsets) when ws allows.
    size_t need_multi = (size_t)BCL * 4 + (size_t)NKEYS_ALL * 8 + (size_t)VDIM * 4 + 4;
    bool multi = ws_size >= need_multi + 256;
    size_t keys_bytes = multi ? ((size_t)NKEYS_ALL * 8 + 255) / 256 * 256
                              : (size_t)32768 * 8;
    float* e_sq     = (float*)(ws + (size_t)BCL * 4 + keys_bytes);
    float* loss_acc = e_sq + VDIM;

    init_kernel<<<dim3((BCL + 255) / 256), 256, 0, stream>>>(
        f, emb, f_rest, f_hat, e_sq, loss_acc, keys, multi ? NKEYS_ALL : 0);

    for (int si = 0; si < 6; ++si) {
        int pl = pls[si];
        int s  = LDIM / pl;
        int NQ = BDIM * pl;
        int qtiles = (NQ + 127) >> 7;
        unsigned long long* k = multi ? keys + qoff[si] : keys;
        if (!multi) hipMemsetAsync(k, 0xFF, (size_t)NQ * 8, stream);
        vq_gemm<<<dim3(qtiles * vch[si]), 256, 0, stream>>>(
            f_rest, emb, e_sq, k, lpls[si], s, NQ, vsb[si], vch[si]);
        fuse_kernel<<<dim3(8, 32), 256, 0, stream>>>(
            f, emb, k, phiw + (size_t)pidx[si] * 3072, phib + (size_t)pidx[si] * 32,
            f_rest, f_hat, loss_acc, pl);
    }
    final_kernel<<<1, 1, 0, stream>>>(loss_acc, out_loss);
}

// Round 6
// 451.650 us; speedup vs baseline: 1.0797x; 1.0797x over previous
//
#include <hip/hip_runtime.h>
#include <stdint.h>

#define BDIM 32
#define CDIM 32
#define LDIM 1024
#define VDIM 4096
#define BCL (BDIM*CDIM*LDIM)

// ---------------------------------------------------------------- init
__global__ void init_kernel(const float* __restrict__ f, const float* __restrict__ emb,
                            float* __restrict__ f_rest, float* __restrict__ f_hat,
                            float* __restrict__ e_sq, float* __restrict__ loss_acc,
                            unsigned* __restrict__ done_ctr,
                            unsigned long long* __restrict__ keys, int nkeys) {
    int i = blockIdx.x * blockDim.x + threadIdx.x;
    if (i < BCL) { f_rest[i] = f[i]; f_hat[i] = 0.0f; }
    if (i < VDIM) {
        const float4* e4 = (const float4*)(emb + (size_t)i * CDIM);
        float s = 0.f;
#pragma unroll
        for (int k = 0; k < 8; ++k) {
            float4 v = e4[k];
            s += v.x*v.x; s += v.y*v.y; s += v.z*v.z; s += v.w*v.w;
        }
        e_sq[i] = s;
    }
    if (i < nkeys) keys[i] = ~0ull;
    if (i == 0) { *loss_acc = 0.f; *done_ctr = 0u; }
}

// ---------------------------------------------------------------- VQ argmin: register-tiled f32 GEMM
// Block: 256 threads (4 waves). Tile: 128 queries x (vsub*256) codes, K=32 staged once.
// Thread tile 8q x 16v -> 0.75 B/FMA LDS traffic. XOR swizzle keeps b128 LDS reads <=2-way.
// REGALLOC HISTORY (rounds 2-5):
//   (256,2)  -> 128 VGPR cap, acc[128] spills to SCRATCH (12.8MB writes), 142us.
//   default / (256,1) -> 136 arch VGPR + acc parked in AGPRs; 136+128=264 > 256 total
//               -> 1 wave/SIMD (occupancy 11%), every LDS latency exposed, 188us.
// FIX: amdgpu_waves_per_eu(2) pins the budget at 256 total regs (acc fits in arch VGPRs),
//      and '#pragma unroll 1' on the k4 loop caps the scheduler's live-range inflation
//      (swizzle becomes a runtime XOR on precomputed per-thread bases - disjoint bit
//      fields, so (base + swz)^ksw == base + (swz^ksw)).
__global__ __attribute__((amdgpu_waves_per_eu(2))) __launch_bounds__(256) void vq_gemm(
    const float* __restrict__ f_rest, const float* __restrict__ emb,
    const float* __restrict__ e_sq, unsigned long long* __restrict__ keys,
    int lpl, int s, int NQ, int vsub, int vchunks)
{
    const int pl = 1 << lpl;
    const int t  = threadIdx.x;
    const int qt = blockIdx.x / vchunks;
    const int vc = blockIdx.x % vchunks;
    const int qb = qt << 7;

    __shared__ __align__(16) float z_s[128*32];
    __shared__ __align__(16) float e_s[256*32];
    __shared__ float esq_s[256];

    // ---- stage z tile (128 queries x 32 channels), swizzled: idx = qp*32 + (c ^ ((qp&7)<<2))
    for (int rep = 0; rep < 16; ++rep) {
        int idx = rep*256 + t;
        int c  = idx >> 7;
        int qp = idx & 127;
        int q  = qb + qp; if (q >= NQ) q = NQ - 1;
        int b  = q >> lpl;
        int j  = q & (pl - 1);
        float zval;
        if (pl == LDIM) {
            zval = f_rest[b*(CDIM*LDIM) + c*LDIM + j];
        } else {
            int col = j*s + (s>>1) - 1;
            const float* p = f_rest + b*(CDIM*LDIM) + c*LDIM + col;
            zval = 0.5f*(p[0] + p[1]);
        }
        z_s[qp*32 + (c ^ ((qp&7)<<2))] = zval;
    }

    const int tq = t & 15;
    const int tv = t >> 4;

    // Precomputed swizzled float-index bases (k4 term XORed in at runtime).
    int zb[8], eb[16];
#pragma unroll
    for (int i = 0; i < 8; ++i) {
        int qp = tq + (i << 4);
        zb[i] = qp*32 + ((qp & 7) << 2);
    }
#pragma unroll
    for (int j = 0; j < 16; ++j) {
        int vp = tv + (j << 4);
        eb[j] = vp*32 + ((vp & 7) << 2);
    }

    float bd[8]; int bv[8];
#pragma unroll
    for (int i = 0; i < 8; ++i) { bd[i] = 3.4e38f; bv[i] = 0; }

    const int VB0 = vc * (vsub << 8);
    for (int sub = 0; sub < vsub; ++sub) {
        const int vb = VB0 + (sub << 8);

        // ---- stage e sub-tile (256 codes x 32 c) + esq, swizzled
        for (int r = 0; r < 8; ++r) {
            int idx = r*256 + t;               // float4 id, 0..2047
            int vp = idx >> 3, cq = idx & 7;
            float4 ev = ((const float4*)emb)[(size_t)(vb + vp)*8 + cq];
            *(float4*)&e_s[vp*32 + ((4*cq) ^ ((vp&7)<<2))] = ev;
        }
        esq_s[t] = e_sq[vb + t];
        __syncthreads();

        float acc[128];
#pragma unroll
        for (int x = 0; x < 128; ++x) acc[x] = 0.f;

#pragma unroll 1
        for (int k4 = 0; k4 < 8; ++k4) {
            const int ksw = k4 << 2;
            float4 zv[8];
#pragma unroll
            for (int i = 0; i < 8; ++i)
                zv[i] = *(const float4*)&z_s[zb[i] ^ ksw];
#pragma unroll
            for (int j = 0; j < 16; ++j) {
                float4 ev = *(const float4*)&e_s[eb[j] ^ ksw];
#pragma unroll
                for (int i = 0; i < 8; ++i) {
                    float a = acc[i*16 + j];
                    a = fmaf(zv[i].x, ev.x, a);
                    a = fmaf(zv[i].y, ev.y, a);
                    a = fmaf(zv[i].z, ev.z, a);
                    a = fmaf(zv[i].w, ev.w, a);
                    acc[i*16 + j] = a;
                }
            }
        }

        // biased distance d' = e_sq - 2*dot (zz constant per query); v ascending -> first-index ties
#pragma unroll
        for (int j = 0; j < 16; ++j) {
            int vp = tv + (j << 4);
            float es = esq_s[vp];
            int v = vb + vp;
#pragma unroll
            for (int i = 0; i < 8; ++i) {
                float d = fmaf(acc[i*16 + j], -2.0f, es);
                if (d < bd[i]) { bd[i] = d; bv[i] = v; }
            }
        }
        __syncthreads();
    }

    // ---- in-block reduction across the 16 tv columns (each holds a disjoint code subset).
    // Reuse e_s as u64[16][128] (16 KB), transposed so the reduce reads are conflict-free.
    unsigned long long* red_s = (unsigned long long*)e_s;
#pragma unroll
    for (int i = 0; i < 8; ++i) {
        unsigned ud = __float_as_uint(bd[i]);
        ud = (ud & 0x80000000u) ? ~ud : (ud | 0x80000000u);   // monotone map (handles negatives)
        red_s[tv*128 + tq + (i << 4)] = ((unsigned long long)ud << 32) | (unsigned)bv[i];
    }
    __syncthreads();
    if (t < 128) {
        unsigned long long best = red_s[t];
#pragma unroll
        for (int m = 1; m < 16; ++m) {
            unsigned long long k2 = red_s[m*128 + t];
            if (k2 < best) best = k2;
        }
        int q = qb + t;
        if (q < NQ) atomicMin(&keys[q], best);
    }
}

// ---------------------------------------------------------------- fused gather+upsample+phi+update+loss
// Also: resets the NEXT scale's key buffer (ping-pong, disjoint from the one it reads),
// and for the last scale finalizes the loss via a done-counter (drops final_kernel).
__global__ __launch_bounds__(256) void fuse_kernel(
    const float* __restrict__ f, const float* __restrict__ emb,
    const unsigned long long* __restrict__ keys,
    unsigned long long* __restrict__ keys_next, int nq_next,
    const float* __restrict__ w, const float* __restrict__ bias,
    float* __restrict__ f_rest, float* __restrict__ f_hat,
    float* __restrict__ loss_acc, unsigned* __restrict__ done_ctr,
    float* __restrict__ out_loss, int pl)
{
    const int t  = threadIdx.x;
    const int b  = blockIdx.y;
    const int l0 = blockIdx.x * 128;

    // reset next scale's keys (different buffer than 'keys'; safe to do immediately)
    if (keys_next) {
        int x = (b * gridDim.x + blockIdx.x) * 256 + t;
        if (x < nq_next) keys_next[x] = ~0ull;
    }

    __shared__ float w_s[3072];      // [o][i][k]
    __shared__ float b_s[32];
    __shared__ float hs[32 * 132];   // [i][130 (+pad)] : col x -> l = l0 - 1 + x
    __shared__ float red[4];

    for (int x = t; x < 3072; x += 256) w_s[x] = w[x];
    if (t < 32) b_s[t] = bias[t];

    if (t < 130) {
        int l = l0 - 1 + t;
        if (l < 0 || l >= LDIM) {
#pragma unroll
            for (int i = 0; i < 32; ++i) hs[i * 132 + t] = 0.f;
        } else {
            int lo, hi; float wg;
            if (pl == LDIM) { lo = l; hi = l; wg = 0.f; }
            else {
                float pos = (l + 0.5f) * ((float)pl / 1024.0f) - 0.5f;
                pos = fminf(fmaxf(pos, 0.f), (float)(pl - 1));
                lo = (int)floorf(pos);
                hi = min(lo + 1, pl - 1);
                wg = pos - (float)lo;
            }
            int v0 = (int)(keys[b * pl + lo] & 0xFFFFFFFFull);
            int v1 = (int)(keys[b * pl + hi] & 0xFFFFFFFFull);
            const float4* e0 = (const float4*)(emb + (size_t)v0 * 32);
            const float4* e1 = (const float4*)(emb + (size_t)v1 * 32);
            float om = 1.0f - wg;
#pragma unroll
            for (int i4 = 0; i4 < 8; ++i4) {
                float4 a = e0[i4]; float4 c = e1[i4];
                hs[(i4*4+0) * 132 + t] = a.x * om + c.x * wg;
                hs[(i4*4+1) * 132 + t] = a.y * om + c.y * wg;
                hs[(i4*4+2) * 132 + t] = a.z * om + c.z * wg;
                hs[(i4*4+3) * 132 + t] = a.w * om + c.w * wg;
            }
        }
    }
    __syncthreads();

    const int o  = t >> 3;        // output channel, fixed per thread (w reuse x16)
    const int lg = t & 7;         // 16 consecutive l's per thread
    const float* wrow = &w_s[o * 96];
    float acc[16];
#pragma unroll
    for (int u = 0; u < 16; ++u) acc[u] = 0.f;
    const int hbase = lg * 16;    // hs col for l = l0 + lg*16 - 1

    for (int i = 0; i < 32; ++i) {
        float w0 = wrow[i * 3 + 0], w1 = wrow[i * 3 + 1], w2 = wrow[i * 3 + 2];
        const float* hrow = &hs[i * 132 + hbase];
        float hw[18];
#pragma unroll
        for (int x = 0; x < 18; ++x) hw[x] = hrow[x];
#pragma unroll
        for (int u = 0; u < 16; ++u) {
            acc[u] = fmaf(w0, hw[u], acc[u]);
            acc[u] = fmaf(w1, hw[u + 1], acc[u]);
            acc[u] = fmaf(w2, hw[u + 2], acc[u]);
        }
    }

    float lsum = 0.f;
    const int gbase = (b * 32 + o) * LDIM + l0 + lg * 16;
#pragma unroll
    for (int u = 0; u < 16; ++u) {
        float hval = hs[o * 132 + lg * 16 + 1 + u];
        float y = acc[u] + b_s[o];
        float ph = 0.5f * hval + 0.5f * y;    // h*(1-RESI) + (conv+b)*RESI, RESI=0.5
        int gi = gbase + u;
        float fh = f_hat[gi] + ph;
        f_hat[gi] = fh;
        f_rest[gi] -= ph;
        float df = fh - f[gi];
        lsum = fmaf(df, df, lsum);
    }

#pragma unroll
    for (int off = 32; off > 0; off >>= 1) lsum += __shfl_down(lsum, off, 64);
    if ((t & 63) == 0) red[t >> 6] = lsum;
    __syncthreads();
    if (t == 0) {
        atomicAdd(loss_acc, red[0] + red[1] + red[2] + red[3]);
        if (out_loss) {
            __threadfence();
            unsigned old = atomicAdd(done_ctr, 1u);
            if (old == (unsigned)(gridDim.x * gridDim.y - 1)) {
                float lv = atomicAdd(loss_acc, 0.0f);   // coherent read after all adds
                *out_loss = lv * (1.25f / (6.0f * (float)BCL));
            }
        }
    }
}

// ---------------------------------------------------------------- launch
extern "C" void kernel_launch(void* const* d_in, const int* in_sizes, int n_in,
                              void* d_out, int out_size, void* d_ws, size_t ws_size,
                              hipStream_t stream)
{
    const float* f    = (const float*)d_in[0];
    const float* emb  = (const float*)d_in[1];
    const float* phiw = (const float*)d_in[2];
    const float* phib = (const float*)d_in[3];

    float* f_hat    = (float*)d_out;        // BCL floats
    float* out_loss = f_hat + BCL;          // +1 float

    const int pls[6]  = {1, 4, 16, 64, 256, 1024};
    const int lpls[6] = {0, 2, 4, 6, 8, 10};
    const int vch[6]  = {16, 16, 16, 16, 8, 2};      // code chunks per query-tile
    const int vsb[6]  = {1, 1, 1, 1, 2, 8};          // 256-code subtiles per block (vch*vsb = 16)
    const int pidx[6] = {0, 0, 1, 2, 3, 3};          // PhiPartiallyShared static tick lookup

    char* ws = (char*)d_ws;
    float* f_rest             = (float*)ws;                            // 4 MB
    unsigned long long* keysA = (unsigned long long*)(ws + (size_t)BCL * 4);   // 256 KB

    // Ping-pong keys (A/B): fuse(si) reads one buffer and resets the other for si+1.
    // No hipMemsetAsync dispatches on the pp path. Fallback: single buffer + memsets.
    size_t need_pp = (size_t)BCL * 4 + (size_t)65536 * 8 + (size_t)VDIM * 4 + 64;
    bool pp = ws_size >= need_pp;
    unsigned long long* keysB = pp ? keysA + 32768 : keysA;
    size_t keys_bytes = pp ? (size_t)65536 * 8 : (size_t)32768 * 8;
    float* e_sq        = (float*)(ws + (size_t)BCL * 4 + keys_bytes);
    float* loss_acc    = e_sq + VDIM;
    unsigned* done_ctr = (unsigned*)(loss_acc + 1);

    init_kernel<<<dim3((BCL + 255) / 256), 256, 0, stream>>>(
        f, emb, f_rest, f_hat, e_sq, loss_acc, done_ctr, keysA, 32768);

    for (int si = 0; si < 6; ++si) {
        int pl = pls[si];
        int s  = LDIM / pl;
        int NQ = BDIM * pl;
        int qtiles = (NQ + 127) >> 7;
        unsigned long long* k  = (si & 1) ? keysB : keysA;
        unsigned long long* kn = (si < 5 && pp) ? ((si & 1) ? keysA : keysB) : nullptr;
        int nq_next = (si < 5) ? BDIM * pls[si + 1] : 0;
        if (!pp && si > 0) hipMemsetAsync(k, 0xFF, (size_t)NQ * 8, stream);
        vq_gemm<<<dim3(qtiles * vch[si]), 256, 0, stream>>>(
            f_rest, emb, e_sq, k, lpls[si], s, NQ, vsb[si], vch[si]);
        fuse_kernel<<<dim3(8, 32), 256, 0, stream>>>(
            f, emb, k, kn, nq_next,
            phiw + (size_t)pidx[si] * 3072, phib + (size_t)pidx[si] * 32,
            f_rest, f_hat, loss_acc, done_ctr,
            (si == 5) ? out_loss : nullptr, pl);
    }
}